// Round 17
// baseline (1052.196 us; speedup 1.0000x reference)
//
#include <hip/hip_runtime.h>

typedef unsigned short u16;
typedef unsigned int u32;

__device__ __forceinline__ float2 up2(u32 u){
  union { u32 i; float f; } a, b;
  a.i = u << 16; b.i = u & 0xffff0000u;
  float2 r; r.x = a.f; r.y = b.f; return r;
}
__device__ __forceinline__ u16 f2bf(float f){
  union { float f; u32 i; } v; v.f = f;
  u32 x = v.i;
  return (u16)((x + 0x7fffu + ((x >> 16) & 1u)) >> 16);
}
__device__ __forceinline__ u32 pk2(float a, float b){
  return (u32)f2bf(a) | ((u32)f2bf(b) << 16);
}
__device__ __forceinline__ float silu_f(float x){ return x / (1.f + __expf(-x)); }
__device__ __forceinline__ float softplus_f(float x){
  return fmaxf(x, 0.f) + log1pf(__expf(-fabsf(x)));
}

// ---- transpose weights, A = -exp(A_log) --------------------------------
__global__ __launch_bounds__(256) void k_prep(
    const float* __restrict__ ipw, const float* __restrict__ xpw,
    const float* __restrict__ dtw, const float* __restrict__ opw,
    const float* __restrict__ w1, const float* __restrict__ w2,
    const float* __restrict__ w3, const float* __restrict__ alog,
    float* __restrict__ ipT, float* __restrict__ xpT,
    float* __restrict__ dtT, float* __restrict__ opT,
    float* __restrict__ w1T, float* __restrict__ w2T,
    float* __restrict__ w3T, float* __restrict__ Aneg)
{
  int t = blockIdx.x * 256 + threadIdx.x;
  if (t < 16384){ int o = t >> 6, c = t & 63; ipT[c * 256 + o] = ipw[t]; }
  if (t < 8192){ int o = t >> 7, d = t & 127; xpT[d * 64 + o] = xpw[t]; }
  if (t < 4096){ int d = t >> 5, r = t & 31; dtT[r * 128 + d] = dtw[t]; }
  if (t < 8192){ int o = t >> 7, d = t & 127; opT[d * 64 + o] = opw[t]; }
  if (t < 4096){ int o = t >> 6, c = t & 63;
                 w1T[c*64+o] = w1[t]; w2T[c*64+o] = w2[t]; w3T[c*64+o] = w3[t]; }
  if (t < 2048){ Aneg[t] = -__expf(alog[t]); }
}

// ---- fully fused: convin + 6 mamba blocks + conv3 ----------------------
// 512 blocks (2/CU). Block owns 16 positions, computes 32 (halo 8/side,
// need 6 for the 6 chained radius-1 convs). 256 threads = 4 waves x
// 8 positions/wave. Lane owns d_inner channels d0=lane, d1=64+lane.
// h state: bf16-packed in VGPRs across all 6 steps: 128 u32/thread.
// ALLOCATOR LAW (measured R2/R8/R12): VGPR budget = 65536/blocksize,
// immune to launch_bounds/waves_per_eu hints (R3/R9/R11 all null).
// 512thr->128, 1024thr->64 both spilled ~1.2-1.7 GB/dispatch.
// 256thr -> 256-VGPR budget; persistent ~160 (h 128 + zs 16 + consts),
// peak ~210 < 256 -> no spill. LDS 72.5 KB -> 2 blocks/CU (VGPR also
// allows 2: 4 waves = 1 wave/SIMD per block at 256 regs).
#define CPB 32
#define PPW 8

__global__ __launch_bounds__(256) void k_fused(
    const float* __restrict__ rgb, const float* __restrict__ dte,
    const float* __restrict__ w1T, const float* __restrict__ b1,
    const float* __restrict__ w2T, const float* __restrict__ b2,
    const float* __restrict__ w3T, const float* __restrict__ b3,
    const float* __restrict__ normw, const float* __restrict__ ipT,
    const float* __restrict__ xpT, const float* __restrict__ dtT,
    const float* __restrict__ opT, const float* __restrict__ Aneg,
    const float* __restrict__ c1w, const float* __restrict__ c1b,
    const float* __restrict__ dtb, const float* __restrict__ Dpw,
    float* __restrict__ outc, float* __restrict__ hfin)
{
  __shared__ __align__(16) float xcp[CPB][128];   // conv input (in_proj x half)
  __shared__ __align__(16) float xcs[CPB][128];   // conv out, reused as y*z
  __shared__ __align__(16) float dblS[CPB][64];   // x_proj out (dt|B|C); later out6
  __shared__ __align__(16) float xns[CPB][64];    // normalized x
  __shared__ __align__(16) float bA[CPB][64];     // rgbp base
  __shared__ __align__(16) float bB[CPB][64];     // dtep base
  __shared__ __align__(16) float ansS[16][129];   // A (s-major, padded)

  const int tid = threadIdx.x;
  const int wv = tid >> 6, lane = tid & 63;
  const int b = blockIdx.x;
  const int batch = b >> 8;
  const int lbase = ((b & 255) << 4) - 8;         // local l of computed pos 0
  const int cpw = wv * PPW;
  const int d0 = lane, d1 = 64 + lane;

  // stage A into LDS (s-major for conflict-free per-q reads)
  for (int i = tid; i < 2048; i += 256) ansS[i & 15][i >> 4] = Aneg[i];

  // per-lane constants
  const float cw00 = c1w[d0*3+0], cw01 = c1w[d0*3+1], cw02 = c1w[d0*3+2];
  const float cw10 = c1w[d1*3+0], cw11 = c1w[d1*3+1], cw12 = c1w[d1*3+2];
  const float cb0 = c1b[d0], cb1 = c1b[d1];
  const float tb0 = dtb[d0], tb1 = dtb[d1];
  const float dp0 = Dpw[d0], dp1 = Dpw[d1];
  const float nw = normw[lane];

  // ---- input 1x1 convs: bA = rgbp, bB = dtep (halo reads clamped) ------
  {
    const float* rp = rgb + (size_t)batch * 262144;
    const float* dq_ = dte + (size_t)batch * 262144;
    int lc[PPW];
    #pragma unroll
    for (int p = 0; p < PPW; p++) lc[p] = min(max(lbase + cpw + p, 0), 4095);
    float accA[PPW], accB[PPW];
    float bb1 = b1[lane], bb2 = b2[lane];
    #pragma unroll
    for (int p = 0; p < PPW; p++){ accA[p] = bb1; accB[p] = bb2; }
    #pragma unroll 2
    for (int c = 0; c < 64; c++){
      float wA = w1T[c*64 + lane], wB = w2T[c*64 + lane];
      const float* rc = rp + c*4096;
      const float* dc = dq_ + c*4096;
      #pragma unroll
      for (int p = 0; p < PPW; p++){
        accA[p] = fmaf(wA, rc[lc[p]], accA[p]);
        accB[p] = fmaf(wB, dc[lc[p]], accB[p]);
      }
    }
    #pragma unroll
    for (int p = 0; p < PPW; p++){ bA[cpw+p][lane] = accA[p]; bB[cpw+p][lane] = accB[p]; }
  }

  // ---- pre: rmsnorm(rgbp) + in_proj -> xcp, zs (step 0 input) ----------
  float zs0[PPW], zs1[PPW];
  {
    #pragma unroll
    for (int p = 0; p < PPW; p++){
      float v = bA[cpw+p][lane];
      float ss = v * v;
      for (int m = 32; m > 0; m >>= 1) ss += __shfl_xor(ss, m);
      v = v * rsqrtf(ss * (1.f/64.f) + 1e-5f) * nw;
      xns[cpw+p][lane] = v;
    }
    float a0[PPW]={}, a1[PPW]={}, a2[PPW]={}, a3[PPW]={};
    #pragma unroll 2
    for (int c = 0; c < 64; c++){
      float w0 = ipT[c*256 + lane];
      float w1 = ipT[c*256 + 64 + lane];
      float w2 = ipT[c*256 + 128 + lane];
      float w3 = ipT[c*256 + 192 + lane];
      #pragma unroll
      for (int p = 0; p < PPW; p++){
        float xv = xns[cpw+p][c];
        a0[p]=fmaf(w0,xv,a0[p]); a1[p]=fmaf(w1,xv,a1[p]);
        a2[p]=fmaf(w2,xv,a2[p]); a3[p]=fmaf(w3,xv,a3[p]);
      }
    }
    #pragma unroll
    for (int p = 0; p < PPW; p++){
      xcp[cpw+p][d0] = a0[p]; xcp[cpw+p][d1] = a1[p];
      zs0[p] = silu_f(a2[p]); zs1[p] = silu_f(a3[p]);
    }
  }

  // h state, bf16-packed (s even -> low, s odd -> high). Zero-init == hasH=0.
  u32 hp0[PPW][8] = {}, hp1[PPW][8] = {};

  #pragma unroll 1
  for (int k = 0; k < 6; k++){
    __syncthreads();                       // all waves' xcp (and ansS) ready

    // depthwise conv(3) + silu; guards: LDS bound (cp) and batch pad (l)
    #pragma unroll
    for (int p = 0; p < PPW; p++){
      int cp = cpw + p;
      int l = lbase + cp;
      float am0=0.f, am1=0.f, ap0=0.f, ap1=0.f;
      if (cp > 0 && l > 0)       { am0 = xcp[cp-1][d0]; am1 = xcp[cp-1][d1]; }
      float a00 = xcp[cp][d0], a01 = xcp[cp][d1];
      if (cp < CPB-1 && l < 4095){ ap0 = xcp[cp+1][d0]; ap1 = xcp[cp+1][d1]; }
      float v0 = silu_f(fmaf(cw00,am0, fmaf(cw01,a00, fmaf(cw02,ap0, cb0))));
      float v1 = silu_f(fmaf(cw10,am1, fmaf(cw11,a01, fmaf(cw12,ap1, cb1))));
      xcs[cp][d0] = v0; xcs[cp][d1] = v1;
    }
    __syncthreads();                       // conv reads done; xcp may be overwritten

    // x_proj -> dblS[cp][o]  (o = lane); weights from global (L2-resident)
    {
      float xa[PPW] = {};
      #pragma unroll 2
      for (int dq = 0; dq < 32; dq++){
        float w0 = xpT[(dq*4+0)*64 + lane], w1 = xpT[(dq*4+1)*64 + lane];
        float w2 = xpT[(dq*4+2)*64 + lane], w3 = xpT[(dq*4+3)*64 + lane];
        #pragma unroll
        for (int p = 0; p < PPW; p++){
          float4 xv = *(const float4*)&xcs[cpw+p][dq*4];
          xa[p] = fmaf(w0,xv.x, fmaf(w1,xv.y, fmaf(w2,xv.z, fmaf(w3,xv.w, xa[p]))));
        }
      }
      #pragma unroll
      for (int p = 0; p < PPW; p++) dblS[cpw+p][lane] = xa[p];
    }

    // dt_proj + softplus; weights from global (L2-resident)
    float dl0[PPW], dl1[PPW];
    {
      float da0[PPW], da1[PPW];
      #pragma unroll
      for (int p = 0; p < PPW; p++){ da0[p] = tb0; da1[p] = tb1; }
      #pragma unroll 2
      for (int r = 0; r < 32; r++){
        float w0 = dtT[r*128 + d0], w1 = dtT[r*128 + d1];
        #pragma unroll
        for (int p = 0; p < PPW; p++){
          float bv = dblS[cpw+p][r];
          da0[p] = fmaf(w0, bv, da0[p]); da1[p] = fmaf(w1, bv, da1[p]);
        }
      }
      #pragma unroll
      for (int p = 0; p < PPW; p++){ dl0[p] = softplus_f(da0[p]); dl1[p] = softplus_f(da1[p]); }
    }

    // h update + y (registers; bf16 repack except last step -> fp32 store)
    float y0[PPW] = {}, y1[PPW] = {};
    float bx0[PPW], bx1[PPW];
    #pragma unroll
    for (int p = 0; p < PPW; p++){
      bx0[p] = dl0[p] * xcs[cpw+p][d0];
      bx1[p] = dl1[p] * xcs[cpw+p][d1];
    }
    if (k < 5){
      #pragma unroll
      for (int q = 0; q < 8; q++){
        float a0e = ansS[2*q][d0], a0o = ansS[2*q+1][d0];
        float a1e = ansS[2*q][d1], a1o = ansS[2*q+1][d1];
        #pragma unroll
        for (int p = 0; p < PPW; p++){
          int cp = cpw + p;
          float2 Bv = *(const float2*)&dblS[cp][32 + 2*q];
          float2 Cv = *(const float2*)&dblS[cp][48 + 2*q];
          float2 h0 = up2(hp0[p][q]);
          float2 h1 = up2(hp1[p][q]);
          float n0e = fmaf(__expf(dl0[p]*a0e), h0.x, bx0[p]*Bv.x);
          float n0o = fmaf(__expf(dl0[p]*a0o), h0.y, bx0[p]*Bv.y);
          float n1e = fmaf(__expf(dl1[p]*a1e), h1.x, bx1[p]*Bv.x);
          float n1o = fmaf(__expf(dl1[p]*a1o), h1.y, bx1[p]*Bv.y);
          y0[p] = fmaf(n0e, Cv.x, y0[p]); y0[p] = fmaf(n0o, Cv.y, y0[p]);
          y1[p] = fmaf(n1e, Cv.x, y1[p]); y1[p] = fmaf(n1o, Cv.y, y1[p]);
          hp0[p][q] = pk2(n0e, n0o);
          hp1[p][q] = pk2(n1e, n1o);
        }
      }
    } else {
      #pragma unroll
      for (int q = 0; q < 8; q++){
        float a0e = ansS[2*q][d0], a0o = ansS[2*q+1][d0];
        float a1e = ansS[2*q][d1], a1o = ansS[2*q+1][d1];
        #pragma unroll
        for (int p = 0; p < PPW; p++){
          int cp = cpw + p;
          float2 Bv = *(const float2*)&dblS[cp][32 + 2*q];
          float2 Cv = *(const float2*)&dblS[cp][48 + 2*q];
          float2 h0 = up2(hp0[p][q]);
          float2 h1 = up2(hp1[p][q]);
          float n0e = fmaf(__expf(dl0[p]*a0e), h0.x, bx0[p]*Bv.x);
          float n0o = fmaf(__expf(dl0[p]*a0o), h0.y, bx0[p]*Bv.y);
          float n1e = fmaf(__expf(dl1[p]*a1e), h1.x, bx1[p]*Bv.x);
          float n1o = fmaf(__expf(dl1[p]*a1o), h1.y, bx1[p]*Bv.y);
          y0[p] = fmaf(n0e, Cv.x, y0[p]); y0[p] = fmaf(n0o, Cv.y, y0[p]);
          y1[p] = fmaf(n1e, Cv.x, y1[p]); y1[p] = fmaf(n1o, Cv.y, y1[p]);
          if (cp >= 8 && cp < 24){
            size_t nI = (size_t)b*16 + (size_t)(cp - 8);
            float2 s0; s0.x = n0e; s0.y = n0o;
            float2 s1; s1.x = n1e; s1.y = n1o;
            *(float2*)(hfin + nI*2048 + (size_t)d0*16 + 2*q) = s0;
            *(float2*)(hfin + nI*2048 + (size_t)d1*16 + 2*q) = s1;
          }
        }
      }
    }

    // finish y (read xcs BEFORE overwrite), gate by silu(z) -> xcs
    #pragma unroll
    for (int p = 0; p < PPW; p++){
      int cp = cpw + p;
      float yy0 = fmaf(dp0, xcs[cp][d0], y0[p]);
      float yy1 = fmaf(dp1, xcs[cp][d1], y1[p]);
      xcs[cp][d0] = yy0 * zs0[p];
      xcs[cp][d1] = yy1 * zs1[p];
    }

    // out_proj
    float oa[PPW] = {};
    #pragma unroll 2
    for (int dq = 0; dq < 32; dq++){
      float w0 = opT[(dq*4+0)*64 + lane], w1 = opT[(dq*4+1)*64 + lane];
      float w2 = opT[(dq*4+2)*64 + lane], w3 = opT[(dq*4+3)*64 + lane];
      #pragma unroll
      for (int p = 0; p < PPW; p++){
        float4 yv = *(const float4*)&xcs[cpw+p][dq*4];
        oa[p] = fmaf(w0,yv.x, fmaf(w1,yv.y, fmaf(w2,yv.z, fmaf(w3,yv.w, oa[p]))));
      }
    }

    if (k < 5){
      // residual + base + rmsnorm + in_proj for next step (xn from LDS)
      const float (*bs_)[64] = (k & 1) ? bA : bB;
      #pragma unroll
      for (int p = 0; p < PPW; p++){
        int cp = cpw + p;
        float v = oa[p] + xns[cp][lane] + bs_[cp][lane];
        float ss = v * v;
        for (int m = 32; m > 0; m >>= 1) ss += __shfl_xor(ss, m);
        v = v * rsqrtf(ss * (1.f/64.f) + 1e-5f) * nw;
        xns[cp][lane] = v;
      }
      float a0[PPW]={}, a1[PPW]={}, a2[PPW]={}, a3[PPW]={};
      #pragma unroll 2
      for (int c = 0; c < 64; c++){
        float w0 = ipT[c*256 + lane];
        float w1 = ipT[c*256 + 64 + lane];
        float w2 = ipT[c*256 + 128 + lane];
        float w3 = ipT[c*256 + 192 + lane];
        #pragma unroll
        for (int p = 0; p < PPW; p++){
          float xv = xns[cpw+p][c];
          a0[p]=fmaf(w0,xv,a0[p]); a1[p]=fmaf(w1,xv,a1[p]);
          a2[p]=fmaf(w2,xv,a2[p]); a3[p]=fmaf(w3,xv,a3[p]);
        }
      }
      #pragma unroll
      for (int p = 0; p < PPW; p++){
        int cp = cpw + p;
        xcp[cp][d0] = a0[p]; xcp[cp][d1] = a1[p];
        zs0[p] = silu_f(a2[p]); zs1[p] = silu_f(a3[p]);
      }
    } else {
      #pragma unroll
      for (int p = 0; p < PPW; p++){
        int cp = cpw + p;
        dblS[cp][lane] = oa[p] + xns[cp][lane];  // out6
      }
    }
  }

  // ---- final 1x1 conv (wave-local rows of dblS) ------------------------
  {
    float o3[PPW];
    float bb3 = b3[lane];
    #pragma unroll
    for (int p = 0; p < PPW; p++) o3[p] = bb3;
    #pragma unroll 2
    for (int cq = 0; cq < 16; cq++){
      float w0 = w3T[(cq*4+0)*64 + lane], w1 = w3T[(cq*4+1)*64 + lane];
      float w2 = w3T[(cq*4+2)*64 + lane], w3v = w3T[(cq*4+3)*64 + lane];
      #pragma unroll
      for (int p = 0; p < PPW; p++){
        float4 vv = *(const float4*)&dblS[cpw+p][cq*4];
        o3[p] = fmaf(w0,vv.x, fmaf(w1,vv.y, fmaf(w2,vv.z, fmaf(w3v,vv.w, o3[p]))));
      }
    }
    #pragma unroll
    for (int p = 0; p < PPW; p++){
      int cp = cpw + p;
      if (cp >= 8 && cp < 24)
        outc[(size_t)batch*262144 + (size_t)lane*4096 + (lbase + cp)] = o3[p];
    }
  }
}

extern "C" void kernel_launch(void* const* d_in, const int* in_sizes, int n_in,
                              void* d_out, int out_size, void* d_ws, size_t ws_size,
                              hipStream_t stream)
{
  const float* rgb  = (const float*)d_in[0];
  const float* dte  = (const float*)d_in[1];
  const float* w1   = (const float*)d_in[2];
  const float* b1   = (const float*)d_in[3];
  const float* w2   = (const float*)d_in[4];
  const float* b2   = (const float*)d_in[5];
  const float* w3   = (const float*)d_in[6];
  const float* b3   = (const float*)d_in[7];
  const float* nrm  = (const float*)d_in[8];
  const float* ipw  = (const float*)d_in[9];
  const float* c1w  = (const float*)d_in[10];
  const float* c1b  = (const float*)d_in[11];
  const float* xpw  = (const float*)d_in[12];
  const float* dtw  = (const float*)d_in[13];
  const float* dtb  = (const float*)d_in[14];
  const float* alog = (const float*)d_in[15];
  const float* Dpw  = (const float*)d_in[16];
  const float* opw  = (const float*)d_in[17];

  float* outc = (float*)d_out;
  float* hfin = outc + 524288;          // final fp32 h lives in d_out

  float* wb   = (float*)d_ws;
  float* ipT  = wb;                     // [64][256]
  float* xpT  = wb + 16384;             // [128][64]
  float* dtT  = wb + 24576;             // [32][128]
  float* opT  = wb + 28672;             // [128][64]
  float* w1T  = wb + 36864;             // [64][64]
  float* w2T  = wb + 40960;
  float* w3T  = wb + 45056;
  float* Aneg = wb + 49152;             // [128][16]

  k_prep<<<64, 256, 0, stream>>>(ipw, xpw, dtw, opw, w1, w2, w3, alog,
                                 ipT, xpT, dtT, opT, w1T, w2T, w3T, Aneg);
  k_fused<<<512, 256, 0, stream>>>(rgb, dte, w1T, b1, w2T, b2, w3T, b3,
                                   nrm, ipT, xpT, dtT, opT, Aneg,
                                   c1w, c1b, dtb, Dpw, outc, hfin);
}

// Round 18
// 399.644 us; speedup vs baseline: 2.6328x; 2.6328x over previous
//
#include <hip/hip_runtime.h>

typedef unsigned short u16;
typedef unsigned int u32;

#define LSEQ 4096
#define NPOS 8192

__device__ __forceinline__ float bf2f(u16 u){
  union { u32 i; float f; } v; v.i = ((u32)u) << 16; return v.f;
}
__device__ __forceinline__ u16 f2bf(float f){
  union { float f; u32 i; } v; v.f = f;
  u32 x = v.i;
  return (u16)((x + 0x7fffu + ((x >> 16) & 1u)) >> 16);
}
__device__ __forceinline__ float2 up2(u32 u){
  union { u32 i; float f; } a, b;
  a.i = u << 16; b.i = u & 0xffff0000u;
  float2 r; r.x = a.f; r.y = b.f; return r;
}
__device__ __forceinline__ u32 pk2(float a, float b){
  return (u32)f2bf(a) | ((u32)f2bf(b) << 16);
}
__device__ __forceinline__ float silu_f(float x){ return x / (1.f + __expf(-x)); }
__device__ __forceinline__ float softplus_f(float x){
  return fmaxf(x, 0.f) + log1pf(__expf(-fabsf(x)));
}

// ---- transpose weights, A = -exp(A_log) --------------------------------
__global__ __launch_bounds__(256) void k_prep(
    const float* __restrict__ ipw, const float* __restrict__ xpw,
    const float* __restrict__ dtw, const float* __restrict__ opw,
    const float* __restrict__ w1, const float* __restrict__ w2,
    const float* __restrict__ w3, const float* __restrict__ alog,
    float* __restrict__ ipT, float* __restrict__ xpT,
    float* __restrict__ dtT, float* __restrict__ opT,
    float* __restrict__ w1T, float* __restrict__ w2T,
    float* __restrict__ w3T, float* __restrict__ Aneg)
{
  int t = blockIdx.x * 256 + threadIdx.x;
  if (t < 16384){ int o = t >> 6, c = t & 63; ipT[c * 256 + o] = ipw[t]; }
  if (t < 8192){ int o = t >> 7, d = t & 127; xpT[d * 64 + o] = xpw[t]; }
  if (t < 4096){ int d = t >> 5, r = t & 31; dtT[r * 128 + d] = dtw[t]; }
  if (t < 8192){ int o = t >> 7, d = t & 127; opT[d * 64 + o] = opw[t]; }
  if (t < 4096){ int o = t >> 6, c = t & 63;
                 w1T[c*64+o] = w1[t]; w2T[c*64+o] = w2[t]; w3T[c*64+o] = w3[t]; }
  if (t < 2048){ Aneg[t] = -__expf(alog[t]); }
}

// ---- input 1x1 convs, LDS-tiled: [B,C,L] -> [N,64] position-major ------
__global__ __launch_bounds__(256) void k_convin(
    const float* __restrict__ rgb, const float* __restrict__ dte,
    const float* __restrict__ w1T, const float* __restrict__ b1,
    const float* __restrict__ w2T, const float* __restrict__ b2,
    float* __restrict__ rgbp, float* __restrict__ dtep)
{
  __shared__ __align__(16) float xt[64][64];
  __shared__ __align__(16) float ot[64][65];
  const int tid = threadIdx.x;
  const int which = blockIdx.x & 1;
  const int n0 = (blockIdx.x >> 1) * 64;
  const int b = n0 >> 12, l0 = n0 & 4095;
  const float* src = which ? dte : rgb;
  const float* wT  = which ? w2T : w1T;
  const float* bb  = which ? b2 : b1;
  float* o = which ? dtep : rgbp;

  #pragma unroll
  for (int j = 0; j < 16; j++){
    int idx = tid + 256 * j;
    int c = idx >> 6, p = idx & 63;
    xt[c][p] = src[(size_t)b * 262144 + (size_t)c * 4096 + l0 + p];
  }
  __syncthreads();

  const int pos = tid & 63;
  const int cb  = (tid >> 6) * 16;
  float acc[16];
  #pragma unroll
  for (int j = 0; j < 16; j++) acc[j] = bb[cb + j];
  for (int c = 0; c < 64; c++){
    float xv = xt[c][pos];
    #pragma unroll
    for (int j = 0; j < 16; j++) acc[j] += wT[c*64 + cb + j] * xv;
  }
  #pragma unroll
  for (int j = 0; j < 16; j++) ot[pos][cb + j] = acc[j];
  __syncthreads();
  #pragma unroll
  for (int j = 0; j < 16; j++){
    int idx = tid + 256 * j;
    int p = idx >> 6, c = idx & 63;
    o[(size_t)(n0 + p)*64 + c] = ot[p][c];
  }
}

// ---- block-0 pre: rmsnorm + in_proj (one wave = 2 positions) -----------
__global__ __launch_bounds__(256) void k_pre(
    const float* __restrict__ xin, const float* __restrict__ normw,
    const float* __restrict__ ipT,
    float* __restrict__ xn, float* __restrict__ xcp, float* __restrict__ zs)
{
  __shared__ __align__(16) float xnl[4][2][64];
  const int wv = threadIdx.x >> 6, lane = threadIdx.x & 63;
  const int n0 = (blockIdx.x * 4 + wv) * 2;
  float nw = normw[lane];
  #pragma unroll
  for (int p = 0; p < 2; p++){
    int n = n0 + p;
    float v = xin[(size_t)n*64 + lane];
    float ss = v * v;
    for (int m = 32; m > 0; m >>= 1) ss += __shfl_xor(ss, m);
    v = v * rsqrtf(ss * (1.f/64.f) + 1e-5f) * nw;
    xn[(size_t)n*64 + lane] = v;
    xnl[wv][p][lane] = v;
  }
  float ac[2][4] = {};
  for (int c = 0; c < 64; c++){
    float w0 = ipT[c*256 + lane],       w1 = ipT[c*256 + 64 + lane];
    float w2 = ipT[c*256 + 128 + lane], w3 = ipT[c*256 + 192 + lane];
    #pragma unroll
    for (int p = 0; p < 2; p++){
      float xv = xnl[wv][p][c];
      ac[p][0] += w0*xv; ac[p][1] += w1*xv; ac[p][2] += w2*xv; ac[p][3] += w3*xv;
    }
  }
  #pragma unroll
  for (int p = 0; p < 2; p++){
    int n = n0 + p;
    xcp[(size_t)n*128 + lane]      = ac[p][0];
    xcp[(size_t)n*128 + 64 + lane] = ac[p][1];
    zs[(size_t)n*128 + lane]       = silu_f(ac[p][2]);
    zs[(size_t)n*128 + 64 + lane]  = silu_f(ac[p][3]);
  }
}

// ---- one Mamba block (+ fused next-block rmsnorm/in_proj) --------------
// one wave = 2 positions; lane owns d0=lane, d1=64+lane of d_inner.
// h is PREFETCHED at kernel entry (hidden under conv/x_proj/dt_proj);
// zero-filled when hasH=0 (bf16 0x0000 unpacks to 0.0f == old branch).
__global__ __launch_bounds__(256) void k_step(
    const float* __restrict__ xcpA, float* __restrict__ xcpB,
    float* __restrict__ zs, float* __restrict__ xn,
    u16* __restrict__ hbf, float* __restrict__ hfin,
    const float* __restrict__ base_next,
    const float* __restrict__ xpT, const float* __restrict__ dtT,
    const float* __restrict__ opT, const float* __restrict__ Aneg,
    const float* __restrict__ c1w, const float* __restrict__ c1b,
    const float* __restrict__ dtb, const float* __restrict__ Dpw,
    const float* __restrict__ normw, const float* __restrict__ ipT,
    int hasH, int fusePre)
{
  __shared__ __align__(16) float xcl[4][2][128];
  __shared__ __align__(16) float dbl[4][2][64];
  __shared__ __align__(16) float yzl[4][2][128];
  __shared__ __align__(16) float xnl[4][2][64];
  const int wv = threadIdx.x >> 6, lane = threadIdx.x & 63;
  const int n0 = (blockIdx.x * 4 + wv) * 2;
  const int d0 = lane, d1 = 64 + lane;

  // ---- PREFETCH h + zs (latency hidden under the phases below) ---------
  uint4 hv[2][4];
  if (hasH){
    #pragma unroll
    for (int p = 0; p < 2; p++){
      const uint4* q0 = (const uint4*)(hbf + ((size_t)(n0+p)*2048 + (size_t)d0*16));
      const uint4* q1 = (const uint4*)(hbf + ((size_t)(n0+p)*2048 + (size_t)d1*16));
      hv[p][0] = q0[0]; hv[p][1] = q0[1];
      hv[p][2] = q1[0]; hv[p][3] = q1[1];
    }
  } else {
    #pragma unroll
    for (int p = 0; p < 2; p++){
      #pragma unroll
      for (int j = 0; j < 4; j++) hv[p][j] = make_uint4(0u,0u,0u,0u);
    }
  }
  float zsv[2][2];
  #pragma unroll
  for (int p = 0; p < 2; p++){
    zsv[p][0] = zs[(size_t)(n0+p)*128 + d0];
    zsv[p][1] = zs[(size_t)(n0+p)*128 + d1];
  }

  float cw00 = c1w[d0*3+0], cw01 = c1w[d0*3+1], cw02 = c1w[d0*3+2];
  float cw10 = c1w[d1*3+0], cw11 = c1w[d1*3+1], cw12 = c1w[d1*3+2];
  float cb0 = c1b[d0], cb1 = c1b[d1];

  // depthwise conv (radius 1 over l within batch) + silu
  float xc0[2], xc1[2];
  #pragma unroll
  for (int p = 0; p < 2; p++){
    int n = n0 + p, l = n & 4095;
    const float* xr = xcpA + (size_t)n * 128;
    float am0 = 0.f, am1 = 0.f, ap0 = 0.f, ap1 = 0.f;
    if (l > 0)    { am0 = xr[d0 - 128]; am1 = xr[d1 - 128]; }
    float a00 = xr[d0], a01 = xr[d1];
    if (l < 4095) { ap0 = xr[d0 + 128]; ap1 = xr[d1 + 128]; }
    float v0 = silu_f(cw00*am0 + cw01*a00 + cw02*ap0 + cb0);
    float v1 = silu_f(cw10*am1 + cw11*a01 + cw12*ap1 + cb1);
    xc0[p] = v0; xc1[p] = v1;
    xcl[wv][p][d0] = v0; xcl[wv][p][d1] = v1;
  }

  // x_proj -> dbc[o=lane]
  {
    float xa[2] = {0,0};
    for (int d = 0; d < 128; d++){
      float w = xpT[d*64 + lane];
      #pragma unroll
      for (int p = 0; p < 2; p++) xa[p] += w * xcl[wv][p][d];
    }
    #pragma unroll
    for (int p = 0; p < 2; p++) dbl[wv][p][lane] = xa[p];
  }

  // dt_proj + softplus
  float dl0[2], dl1[2];
  {
    float tb0 = dtb[d0], tb1 = dtb[d1];
    float da0[2] = {tb0, tb0}, da1[2] = {tb1, tb1};
    for (int r = 0; r < 32; r++){
      float w0 = dtT[r*128 + d0], w1 = dtT[r*128 + d1];
      #pragma unroll
      for (int p = 0; p < 2; p++){
        float bv = dbl[wv][p][r];
        da0[p] += w0 * bv; da1[p] += w1 * bv;
      }
    }
    #pragma unroll
    for (int p = 0; p < 2; p++){ dl0[p] = softplus_f(da0[p]); dl1[p] = softplus_f(da1[p]); }
  }

  float an0[16], an1[16];
  {
    const float4* A0 = (const float4*)(Aneg + d0*16);
    const float4* A1 = (const float4*)(Aneg + d1*16);
    #pragma unroll
    for (int q = 0; q < 4; q++){
      float4 a = A0[q]; an0[q*4+0]=a.x; an0[q*4+1]=a.y; an0[q*4+2]=a.z; an0[q*4+3]=a.w;
      float4 b = A1[q]; an1[q*4+0]=b.x; an1[q*4+1]=b.y; an1[q*4+2]=b.z; an1[q*4+3]=b.w;
    }
  }
  float dp0 = Dpw[d0], dp1 = Dpw[d1];

  // h update (prefetched bf16 state; fp32 final to d_out) + y
  #pragma unroll
  for (int p = 0; p < 2; p++){
    int n = n0 + p;
    float Bm[16], Cm[16];
    {
      const float4* bb = (const float4*)&dbl[wv][p][32];
      const float4* cc = (const float4*)&dbl[wv][p][48];
      #pragma unroll
      for (int q = 0; q < 4; q++){
        float4 a = bb[q]; Bm[q*4+0]=a.x; Bm[q*4+1]=a.y; Bm[q*4+2]=a.z; Bm[q*4+3]=a.w;
        float4 b = cc[q]; Cm[q*4+0]=b.x; Cm[q*4+1]=b.y; Cm[q*4+2]=b.z; Cm[q*4+3]=b.w;
      }
    }
    u16* hp0 = hbf + ((size_t)n*2048 + (size_t)d0*16);
    u16* hp1 = hbf + ((size_t)n*2048 + (size_t)d1*16);
    float h0[16], h1[16];
    {
      #pragma unroll
      for (int q = 0; q < 2; q++){
        uint4 v = hv[p][q];
        float2 t0=up2(v.x), t1=up2(v.y), t2=up2(v.z), t3=up2(v.w);
        h0[q*8+0]=t0.x; h0[q*8+1]=t0.y; h0[q*8+2]=t1.x; h0[q*8+3]=t1.y;
        h0[q*8+4]=t2.x; h0[q*8+5]=t2.y; h0[q*8+6]=t3.x; h0[q*8+7]=t3.y;
        uint4 w = hv[p][2+q];
        float2 s0=up2(w.x), s1=up2(w.y), s2=up2(w.z), s3=up2(w.w);
        h1[q*8+0]=s0.x; h1[q*8+1]=s0.y; h1[q*8+2]=s1.x; h1[q*8+3]=s1.y;
        h1[q*8+4]=s2.x; h1[q*8+5]=s2.y; h1[q*8+6]=s3.x; h1[q*8+7]=s3.y;
      }
    }
    float y0 = 0.f, y1 = 0.f;
    float bx0 = dl0[p] * xc0[p], bx1 = dl1[p] * xc1[p];
    #pragma unroll
    for (int s = 0; s < 16; s++){
      h0[s] = __expf(dl0[p]*an0[s])*h0[s] + bx0*Bm[s];
      y0 = fmaf(h0[s], Cm[s], y0);
      h1[s] = __expf(dl1[p]*an1[s])*h1[s] + bx1*Bm[s];
      y1 = fmaf(h1[s], Cm[s], y1);
    }
    if (fusePre){
      #pragma unroll
      for (int q = 0; q < 2; q++){
        uint4 v;
        v.x = pk2(h0[q*8+0], h0[q*8+1]); v.y = pk2(h0[q*8+2], h0[q*8+3]);
        v.z = pk2(h0[q*8+4], h0[q*8+5]); v.w = pk2(h0[q*8+6], h0[q*8+7]);
        ((uint4*)hp0)[q] = v;
        uint4 w;
        w.x = pk2(h1[q*8+0], h1[q*8+1]); w.y = pk2(h1[q*8+2], h1[q*8+3]);
        w.z = pk2(h1[q*8+4], h1[q*8+5]); w.w = pk2(h1[q*8+6], h1[q*8+7]);
        ((uint4*)hp1)[q] = w;
      }
    } else {
      float4* f0 = (float4*)(hfin + (size_t)n*2048 + (size_t)d0*16);
      float4* f1 = (float4*)(hfin + (size_t)n*2048 + (size_t)d1*16);
      #pragma unroll
      for (int q = 0; q < 4; q++){
        float4 v; v.x=h0[q*4+0]; v.y=h0[q*4+1]; v.z=h0[q*4+2]; v.w=h0[q*4+3];
        f0[q] = v;
        float4 w; w.x=h1[q*4+0]; w.y=h1[q*4+1]; w.z=h1[q*4+2]; w.w=h1[q*4+3];
        f1[q] = w;
      }
    }
    y0 += dp0 * xc0[p];
    y1 += dp1 * xc1[p];
    yzl[wv][p][d0] = y0 * zsv[p][0];
    yzl[wv][p][d1] = y1 * zsv[p][1];
  }

  // out_proj
  float oa[2] = {0,0};
  for (int d = 0; d < 128; d++){
    float w = opT[d*64 + lane];
    #pragma unroll
    for (int p = 0; p < 2; p++) oa[p] += w * yzl[wv][p][d];
  }

  float nw = normw[lane];
  if (fusePre){
    #pragma unroll
    for (int p = 0; p < 2; p++){
      int n = n0 + p;
      float v = oa[p] + xn[(size_t)n*64 + lane] + base_next[(size_t)n*64 + lane];
      float ss = v * v;
      for (int m = 32; m > 0; m >>= 1) ss += __shfl_xor(ss, m);
      v = v * rsqrtf(ss * (1.f/64.f) + 1e-5f) * nw;
      xn[(size_t)n*64 + lane] = v;
      xnl[wv][p][lane] = v;
    }
    float ac[2][4] = {};
    for (int c = 0; c < 64; c++){
      float w0 = ipT[c*256 + lane],       w1 = ipT[c*256 + 64 + lane];
      float w2 = ipT[c*256 + 128 + lane], w3 = ipT[c*256 + 192 + lane];
      #pragma unroll
      for (int p = 0; p < 2; p++){
        float xv = xnl[wv][p][c];
        ac[p][0] += w0*xv; ac[p][1] += w1*xv; ac[p][2] += w2*xv; ac[p][3] += w3*xv;
      }
    }
    #pragma unroll
    for (int p = 0; p < 2; p++){
      int n = n0 + p;
      xcpB[(size_t)n*128 + lane]      = ac[p][0];
      xcpB[(size_t)n*128 + 64 + lane] = ac[p][1];
      zs[(size_t)n*128 + lane]        = silu_f(ac[p][2]);
      zs[(size_t)n*128 + 64 + lane]   = silu_f(ac[p][3]);
    }
  } else {
    #pragma unroll
    for (int p = 0; p < 2; p++){
      int n = n0 + p;
      xcpB[(size_t)n*64 + lane] = oa[p] + xn[(size_t)n*64 + lane];
    }
  }
}

// ---- final conv1x1, transpose [N,64] -> [B,64,L] -----------------------
__global__ __launch_bounds__(256) void k_conv3(
    const float* __restrict__ out6, const float* __restrict__ w3T,
    const float* __restrict__ b3, float* __restrict__ out)
{
  __shared__ __align__(16) float t[64][65];
  const int tid = threadIdx.x;
  const int n0 = blockIdx.x * 64;
  #pragma unroll
  for (int i = 0; i < 16; i++){
    int idx = tid + 256*i;
    int r = idx >> 6, c = idx & 63;
    t[r][c] = out6[(size_t)(n0 + r)*64 + c];
  }
  __syncthreads();
  const int i = tid & 63;
  const int cb = (tid >> 6) * 16;
  float acc[16];
  #pragma unroll
  for (int j = 0; j < 16; j++) acc[j] = b3[cb + j];
  for (int o = 0; o < 64; o++){
    float xv = t[i][o];
    #pragma unroll
    for (int j = 0; j < 16; j++) acc[j] += w3T[o*64 + cb + j] * xv;
  }
  const int b = n0 >> 12;
  const int l = (n0 & 4095) + i;
  #pragma unroll
  for (int j = 0; j < 16; j++)
    out[(size_t)b*262144 + (size_t)(cb + j)*4096 + l] = acc[j];
}

extern "C" void kernel_launch(void* const* d_in, const int* in_sizes, int n_in,
                              void* d_out, int out_size, void* d_ws, size_t ws_size,
                              hipStream_t stream)
{
  const float* rgb  = (const float*)d_in[0];
  const float* dte  = (const float*)d_in[1];
  const float* w1   = (const float*)d_in[2];
  const float* b1   = (const float*)d_in[3];
  const float* w2   = (const float*)d_in[4];
  const float* b2   = (const float*)d_in[5];
  const float* w3   = (const float*)d_in[6];
  const float* b3   = (const float*)d_in[7];
  const float* nrm  = (const float*)d_in[8];
  const float* ipw  = (const float*)d_in[9];
  const float* c1w  = (const float*)d_in[10];
  const float* c1b  = (const float*)d_in[11];
  const float* xpw  = (const float*)d_in[12];
  const float* dtw  = (const float*)d_in[13];
  const float* dtb  = (const float*)d_in[14];
  const float* alog = (const float*)d_in[15];
  const float* Dpw  = (const float*)d_in[16];
  const float* opw  = (const float*)d_in[17];

  float* outc = (float*)d_out;
  float* hfin = outc + 524288;          // final fp32 h lives in d_out

  float* ws   = (float*)d_ws;
  float* xcp0 = ws;                     // [N,128] ping
  float* xcp1 = ws + 1048576;           // [N,128] pong
  float* rgbp = ws + 2097152;           // [N,64]
  float* dtep = ws + 2621440;           // [N,64]
  float* xnb  = ws + 3145728;           // [N,64]
  float* zsb  = ws + 3670016;           // [N,128]
  float* wb   = ws + 4718592;           // transposed weights
  float* ipT  = wb;                     // [64][256]
  float* xpT  = wb + 16384;             // [128][64]
  float* dtT  = wb + 24576;             // [32][128]
  float* opT  = wb + 28672;             // [128][64]
  float* w1T  = wb + 36864;             // [64][64]
  float* w2T  = wb + 40960;
  float* w3T  = wb + 45056;
  float* Aneg = wb + 49152;             // [128][16]
  u16*   hbf  = (u16*)(ws + 4769792);   // [N,128,16] bf16 intermediate h

  k_prep<<<64, 256, 0, stream>>>(ipw, xpw, dtw, opw, w1, w2, w3, alog,
                                 ipT, xpT, dtT, opT, w1T, w2T, w3T, Aneg);
  k_convin<<<256, 256, 0, stream>>>(rgb, dte, w1T, b1, w2T, b2, rgbp, dtep);
  k_pre<<<1024, 256, 0, stream>>>(rgbp, nrm, ipT, xnb, xcp0, zsb);

  float* xa[2] = {xcp0, xcp1};
  for (int k = 0; k < 6; k++){
    const float* base = (k == 5) ? rgbp /*unused*/ : ((k & 1) ? rgbp : dtep);
    k_step<<<1024, 256, 0, stream>>>(xa[k & 1], xa[(k & 1) ^ 1], zsb, xnb,
                                     hbf, hfin, base,
                                     xpT, dtT, opT, Aneg, c1w, c1b, dtb, Dpw,
                                     nrm, ipT, (k > 0) ? 1 : 0, (k < 5) ? 1 : 0);
  }
  k_conv3<<<128, 256, 0, stream>>>(xcp0, w3T, b3, outc);
}